// Round 10
// baseline (2926.078 us; speedup 1.0000x reference)
//
#include <hip/hip_runtime.h>

// ---------------------------------------------------------------------------
// Encoder: x=emb[enc]; xp = x@Wx + b_in; reset-after GRU over T=256 steps;
// out = h_last[:, 200:700].  All float inputs fp32; output fp32.
//
// Persistent weight-stationary GRU, per-WAVE dataflow sync (R11 fabric):
//   - Consumer wave rt reads ONLY its own 16 rows, produced by same-rt waves
//     of the 22 producer blocks. Producer drains own stores (vmcnt(0) is
//     wave-local) then publishes flag[g][slice][wave] (relaxed agent store);
//     consumer polls its 44 flags lane-parallel (relaxed agent loads), then
//     l1_inv + plain b128 A-loads. NO __syncthreads in the 256-step loop.
//   - 176 blocks; swizzle g=bx&7, s=bx>>3; HW_REG_XCC_ID check selects fast
//     (same-XCD group) or slow (release/acquire agent) per group.
//   - d_ws: [8] grid barrier, [16..191] xcc, [256..1279] wave flags.
//
// Evidence ledger:
//   - R12: VALU heaters on 80 idle CUs = exact null -> DVFS theory dead.
//   - R13: fast=TRUE; dependent-FMA chain added FULL nominal cost -> full
//     clock; ~20K cyc/step = serial per-wave stream S + small hop h.
//   - R15: agent atomics bypass L1 AND L2 (coherence point = L3/MALL).
//   - R17: sc0-only flags never observed; NO cheap L2-level cross-block
//     observation primitive. Fabric stays agent-relaxed + l1_inv.
//   - R18 probe: RT_agent ~570-900 cyc; flag hop NOT the missing ~13K.
//   - R19: nt emb loads regressed (destroyed 22x L2 reuse). KEY: VGPR stayed
//     68 at __launch_bounds__(256,1) — declared prefetch structures were
//     never materialized; compiler's pressure heuristic sank all loads to
//     just-before-use. LDS caps us at 1 block/CU => 1 wave/SIMD, so we run
//     a serial stream with ~2-slot lookahead: ~22 exposed A-load latencies
//     (~200-900cyc each) per step = the missing ~10K+ cycles.
//   - R20: amdgpu_waves_per_eu(1,1) DOES raise allocator acceptance
//     (68->180 VGPR) and the B-hoist DID kill h-loop LDS conflicts
//     (5.755e7 -> 1.015e7 = exactly the x-part's 12/78 share). BUT 264
//     VGPRs of LOOP-CARRIED B arrays exceeded the heuristic => spilled to
//     scratch; h-loop reloaded B from scratch = +2.9us/step regression.
//     Lessons: attribute works; loop-carried mega-arrays spill; LDS
//     conflicts were NOT the dominant term (<few hundred cyc/step).
//   - R21 (this round): B-hoist REVERTED (B in LDS). Keep the attribute.
//     FULL A-prefetch ra[22]/rb[22] (176 VGPRs, INTRA-iteration lifetime —
//     allocator-friendly, ~260 peak, no spill expected): all 44 A-loads
//     issue back-to-back so ONE max-latency exposure per step replaces ~22
//     serial exposures. emb prefetch after the A-batch (FIFO vmcnt).
//     Materialization check: VGPR ~230-280 = real test of the A-latency
//     theory; VGPR ~80-120 = void again. If dur unchanged at high VGPR,
//     A-latency wasn't binding -> next round: l1_inv differential probe.
// ---------------------------------------------------------------------------

typedef unsigned short ushort_t;
typedef __bf16 bf16x8 __attribute__((ext_vector_type(8)));
typedef unsigned short ushort8 __attribute__((ext_vector_type(8)));
typedef float floatx4 __attribute__((ext_vector_type(4)));

#define NGRP   8
#define NSLC   22
#define NBLK   176
#define SB     840   // LDS row stride (bf16): 832 + 8 pad
#define HP     704
#define AH_ROW 1408  // hi[704] | lo[704]
#define PHASE  (256 * AH_ROW)
#define FLAGW(gg, ss, ww) (256 + (gg) * 128 + (ss) * 4 + (ww))

__device__ __forceinline__ float bf2f(ushort_t u) {
    unsigned v = ((unsigned)u) << 16; float f; __builtin_memcpy(&f, &v, 4); return f;
}
__device__ __forceinline__ ushort_t f2bf(float f) {
    unsigned u; __builtin_memcpy(&u, &f, 4);
    unsigned r = u + 0x7fff + ((u >> 16) & 1);
    return (ushort_t)(r >> 16);
}
__device__ __forceinline__ bf16x8 ld8(const ushort_t* p) {
    return __builtin_bit_cast(bf16x8, *(const ushort8*)p);
}
__device__ __forceinline__ bf16x8 cvt8(floatx4 a, floatx4 b) {
    ushort8 r = {f2bf(a.x), f2bf(a.y), f2bf(a.z), f2bf(a.w),
                 f2bf(b.x), f2bf(b.y), f2bf(b.z), f2bf(b.w)};
    return __builtin_bit_cast(bf16x8, r);
}
__device__ __forceinline__ void l1_inv() {
    asm volatile("buffer_inv sc0" ::: "memory");
}
__device__ __forceinline__ void wave_drain() {   // wave-local store drain
    asm volatile("s_waitcnt vmcnt(0)" ::: "memory");
}
__device__ __forceinline__ float fast_rcp(float x) {
    float r; asm("v_rcp_f32 %0, %1" : "=v"(r) : "v"(x)); return r;
}
__device__ __forceinline__ float fast_exp(float x) {
    float r; asm("v_exp_f32 %0, %1" : "=v"(r) : "v"(x * 1.44269504f)); return r;
}

__global__ void init_cnt(int* cnt) {
    for (int i = threadIdx.x; i < 1280; i += 1024) cnt[i] = 0;
}

__global__ __attribute__((amdgpu_waves_per_eu(1, 1)))
__launch_bounds__(256) void gru_main(
    const int* __restrict__ enc, const float* __restrict__ emb,
    const float* __restrict__ Wx, float* whf,
    const float* __restrict__ lab, const float* __restrict__ W1,
    const float* __restrict__ b1, const float* __restrict__ bias,
    float* __restrict__ out, int* cnt) {

    extern __shared__ ushort_t Bs[];   // [96][SB] bf16
    const int bx = blockIdx.x;
    const int g = bx & 7, s = bx >> 3;
    const int tid = threadIdx.x;
    const int wave = tid >> 6, lane = tid & 63;
    const int rt = wave >> 1, ct = wave & 1;
    const int q = lane >> 4, m = lane & 15;

    // ---- one-time staging: Bs[p][k] = bf16(W[k][col(p)]), p = gate*32+c ----
    for (int idx = tid; idx < 96 * 832; idx += 256) {
        int p = idx % 96, k = idx / 96;
        int c = s * 32 + (p & 31);
        ushort_t v = 0;
        if (c < 700) {
            int col = (p >> 5) * 700 + c;
            if (k < 100) v = f2bf(Wx[k * 2100 + col]);
            else if (k >= 128 && k < 828) v = f2bf(whf[(k - 128) * 2100 + col]);
        }
        Bs[p * SB + k] = v;
    }
    __syncthreads();   // all Wh reads of this block retired

    // ---- publish xcc id, then grid barrier (agent scope, one-time) ---------
    if (tid == 0) {
        int xcc;
        asm("s_getreg_b32 %0, hwreg(HW_REG_XCC_ID)" : "=s"(xcc));
        __hip_atomic_store(cnt + 16 + bx, xcc, __ATOMIC_RELAXED, __HIP_MEMORY_SCOPE_AGENT);
        __hip_atomic_fetch_add(cnt + 8, 1, __ATOMIC_ACQ_REL, __HIP_MEMORY_SCOPE_AGENT);
        while (__hip_atomic_load(cnt + 8, __ATOMIC_ACQUIRE, __HIP_MEMORY_SCOPE_AGENT) < NBLK)
            __builtin_amdgcn_s_sleep(1);
    }
    __syncthreads();

    // ---- fast iff all 22 peers share an XCD --------------------------------
    bool fast = true;
    {
        int myx = __hip_atomic_load(cnt + 16 + bx, __ATOMIC_RELAXED, __HIP_MEMORY_SCOPE_AGENT);
        for (int s2 = 0; s2 < NSLC; ++s2) {
            int px = __hip_atomic_load(cnt + 16 + g + 8 * s2, __ATOMIC_RELAXED, __HIP_MEMORY_SCOPE_AGENT);
            fast = fast && (px == myx);
        }
    }

    const int j = s * 32 + ct * 16 + m;
    float bzc = 0.f, brc = 0.f, b0h = 0.f, b1h = 0.f;
    if (j < 700) {
        bzc = bias[j] + bias[2100 + j];
        brc = bias[700 + j] + bias[2800 + j];
        b0h = bias[1400 + j];
        b1h = bias[3500 + j];
    }
    const int rowa = g * 32 + rt * 16 + m;

    ushort_t* Ah = (ushort_t*)whf;
    int* myflag = cnt + FLAGW(g, s, wave);
    // consumer wave rt needs flags (s2, rt*2+ct') for s2=0..21, ct'=0..1
    int* pollp = (lane < 44)
               ? (cnt + FLAGW(g, lane >> 1, rt * 2 + (lane & 1)))
               : (int*)nullptr;

    // ---- h0; publish hi/lo to phase 0 (per-wave) ---------------------------
    float hown[4];
#pragma unroll
    for (int i = 0; i < 4; i++) {
        int rowc = g * 32 + rt * 16 + q * 4 + i;
        float v = 0.f;
        if (j < 200) v = lab[rowc] * W1[j] + b1[j];
        hown[i] = v;
        ushort_t hi = f2bf(v);
        Ah[rowc * AH_ROW + j] = hi;
        Ah[rowc * AH_ROW + HP + j] = f2bf(v - bf2f(hi));
    }
    if (fast) {
        wave_drain();
        if (lane == 0)
            __hip_atomic_store(myflag, 1, __ATOMIC_RELAXED, __HIP_MEMORY_SCOPE_AGENT);
    } else {
        if (lane == 0)
            __hip_atomic_store(myflag, 1, __ATOMIC_RELEASE, __HIP_MEMORY_SCOPE_AGENT);
        else
            __threadfence();
    }

    const ushort_t* bsz = Bs + (ct * 16 + m) * SB;
    const ushort_t* bsr = Bs + (32 + ct * 16 + m) * SB;
    const ushort_t* bsh = Bs + (64 + ct * 16 + m) * SB;

    // ---- initial x prefetch for t=0 (plain: emb rows have 22x L2 reuse) ----
    floatx4 pf[6]; floatx4 pft;
    {
        int tok = enc[rowa * 256 + 0];
        const float* ep = emb + tok * 100;
#pragma unroll
        for (int kt = 0; kt < 3; ++kt) {
            pf[kt * 2]     = *(const floatx4*)(ep + kt * 32 + q * 8);
            pf[kt * 2 + 1] = *(const floatx4*)(ep + kt * 32 + q * 8 + 4);
        }
        pft = *(const floatx4*)(ep + 96);
    }

    for (int t = 0; t < 256; ++t) {
        const ushort_t* Asrc = Ah + (t & 1) * PHASE;
        ushort_t* Adst = Ah + ((t + 1) & 1) * PHASE;
        floatx4 accz = {0,0,0,0}, accr = {0,0,0,0}, accrh = {0,0,0,0}, accxh = {0,0,0,0};

        // x-part from prefetched registers (off the critical chain)
#pragma unroll
        for (int kt = 0; kt < 3; ++kt) {
            bf16x8 a = cvt8(pf[kt * 2], pf[kt * 2 + 1]);
            int kb = kt * 32 + q * 8;
            accz  = __builtin_amdgcn_mfma_f32_16x16x32_bf16(a, ld8(bsz + kb), accz, 0, 0, 0);
            accr  = __builtin_amdgcn_mfma_f32_16x16x32_bf16(a, ld8(bsr + kb), accr, 0, 0, 0);
            accxh = __builtin_amdgcn_mfma_f32_16x16x32_bf16(a, ld8(bsh + kb), accxh, 0, 0, 0);
        }
        {
            ushort8 t8 = {0, 0, 0, 0, 0, 0, 0, 0};
            if (q == 0) {
                t8[0] = f2bf(pft.x); t8[1] = f2bf(pft.y);
                t8[2] = f2bf(pft.z); t8[3] = f2bf(pft.w);
            }
            bf16x8 a = __builtin_bit_cast(bf16x8, t8);
            int kb = 96 + q * 8;
            accz  = __builtin_amdgcn_mfma_f32_16x16x32_bf16(a, ld8(bsz + kb), accz, 0, 0, 0);
            accr  = __builtin_amdgcn_mfma_f32_16x16x32_bf16(a, ld8(bsr + kb), accr, 0, 0, 0);
            accxh = __builtin_amdgcn_mfma_f32_16x16x32_bf16(a, ld8(bsh + kb), accxh, 0, 0, 0);
        }

        // wait (per-wave, lane-parallel over the 44 relevant producer waves).
        // Poll enters with ZERO outstanding vmem.
        if (lane < 44) {
            if (fast) {
                int spin = 0;
                while (__hip_atomic_load(pollp, __ATOMIC_RELAXED, __HIP_MEMORY_SCOPE_AGENT) < t + 1) {
                    if (++spin > 64) __builtin_amdgcn_s_sleep(1);
                }
            } else {
                while (__hip_atomic_load(pollp, __ATOMIC_ACQUIRE, __HIP_MEMORY_SCOPE_AGENT) < t + 1)
                    __builtin_amdgcn_s_sleep(1);
            }
        }
        if (fast) l1_inv();   // fresh L1 for this wave's h reads

        // h-part A-loads: FULL prefetch of all 22 hi/lo frag pairs (44 x 16B
        // back-to-back; intra-iteration lifetime => allocator-friendly).
        // ONE max-latency exposure per step instead of ~22 serial exposures.
        const ushort_t* arow = Asrc + rowa * AH_ROW + q * 8;
        bf16x8 ra[22], rb[22];
#pragma unroll
        for (int p = 0; p < 22; ++p) {
            ra[p] = ld8(arow + p * 32);
            rb[p] = ld8(arow + HP + p * 32);
        }

        // prefetch x for t+1 (plain loads, issued AFTER the A-batch so the
        // A-waits' vmcnt values exclude emb; drains at the publish vmcnt(0))
        {
            int tn = (t < 255) ? t + 1 : 255;
            int tok = enc[rowa * 256 + tn];
            const float* ep = emb + tok * 100;
#pragma unroll
            for (int kt = 0; kt < 3; ++kt) {
                pf[kt * 2]     = *(const floatx4*)(ep + kt * 32 + q * 8);
                pf[kt * 2 + 1] = *(const floatx4*)(ep + kt * 32 + q * 8 + 4);
            }
            pft = *(const floatx4*)(ep + 96);
        }

        // h-loop: B from LDS (R20 proved conflicts are not the binding term)
#pragma unroll
        for (int kt = 0; kt < 22; ++kt) {
            int kb = 128 + kt * 32 + q * 8;
            bf16x8 bz8 = ld8(bsz + kb), br8 = ld8(bsr + kb), bh8 = ld8(bsh + kb);
            accz  = __builtin_amdgcn_mfma_f32_16x16x32_bf16(ra[kt], bz8, accz, 0, 0, 0);
            accr  = __builtin_amdgcn_mfma_f32_16x16x32_bf16(ra[kt], br8, accr, 0, 0, 0);
            accrh = __builtin_amdgcn_mfma_f32_16x16x32_bf16(ra[kt], bh8, accrh, 0, 0, 0);
            accz  = __builtin_amdgcn_mfma_f32_16x16x32_bf16(rb[kt], bz8, accz, 0, 0, 0);
            accr  = __builtin_amdgcn_mfma_f32_16x16x32_bf16(rb[kt], br8, accr, 0, 0, 0);
            accrh = __builtin_amdgcn_mfma_f32_16x16x32_bf16(rb[kt], bh8, accrh, 0, 0, 0);
        }

        // epilogue: fast gates, update h, publish hi/lo
#pragma unroll
        for (int i = 0; i < 4; i++) {
            int rowc = g * 32 + rt * 16 + q * 4 + i;
            float z = fast_rcp(1.f + fast_exp(-(accz[i] + bzc)));
            float r = fast_rcp(1.f + fast_exp(-(accr[i] + brc)));
            float e2 = fast_exp(2.f * (accxh[i] + b0h + r * (accrh[i] + b1h)));
            float hh = 1.f - 2.f * fast_rcp(e2 + 1.f);
            float h = z * hown[i] + (1.f - z) * hh;
            if (j >= 700) h = 0.f;
            hown[i] = h;
            ushort_t hi = f2bf(h);
            Adst[rowc * AH_ROW + j] = hi;
            Adst[rowc * AH_ROW + HP + j] = f2bf(h - bf2f(hi));
        }

        // per-wave publish: drain own stores, then flag
        if (fast) {
            wave_drain();
            if (lane == 0)
                __hip_atomic_store(myflag, t + 2, __ATOMIC_RELAXED, __HIP_MEMORY_SCOPE_AGENT);
        } else {
            if (lane == 0)
                __hip_atomic_store(myflag, t + 2, __ATOMIC_RELEASE, __HIP_MEMORY_SCOPE_AGENT);
            else
                __threadfence();
        }
    }

    // ---- final output -------------------------------------------------------
#pragma unroll
    for (int i = 0; i < 4; i++) {
        int rowc = g * 32 + rt * 16 + q * 4 + i;
        if (j >= 200 && j < 700)
            out[rowc * 500 + (j - 200)] = hown[i];
    }
}

extern "C" void kernel_launch(void* const* d_in, const int* in_sizes, int n_in,
                              void* d_out, int out_size, void* d_ws, size_t ws_size,
                              hipStream_t stream) {
    (void)in_sizes; (void)n_in; (void)out_size; (void)ws_size;
    const int*   enc  = (const int*)d_in[0];
    const float* lab  = (const float*)d_in[1];
    const float* emb  = (const float*)d_in[2];
    const float* W1   = (const float*)d_in[3];
    const float* b1   = (const float*)d_in[4];
    const float* Wx   = (const float*)d_in[5];
    float*       Wh   = (float*)d_in[6];
    const float* bias = (const float*)d_in[7];

    int*   cnt = (int*)d_ws;               // 5.2 KB of scratch used
    float* out = (float*)d_out;

    init_cnt<<<1, 1024, 0, stream>>>(cnt);

    hipFuncSetAttribute((const void*)gru_main,
                        hipFuncAttributeMaxDynamicSharedMemorySize, 96 * SB * 2);
    gru_main<<<NBLK, 256, 96 * SB * 2, stream>>>(enc, emb, Wx, Wh, lab, W1, b1,
                                                 bias, out, cnt);
}

// Round 11
// 1940.700 us; speedup vs baseline: 1.5077x; 1.5077x over previous
//
#include <hip/hip_runtime.h>

// ---------------------------------------------------------------------------
// Encoder: x=emb[enc]; xp = x@Wx + b_in; reset-after GRU over T=256 steps;
// out = h_last[:, 200:700].  All float inputs fp32; output fp32.
//
// Persistent weight-stationary GRU, per-WAVE dataflow sync (R11 fabric):
//   - Consumer wave rt reads ONLY its own 16 rows, produced by same-rt waves
//     of the 22 producer blocks. Producer drains own stores (vmcnt(0) is
//     wave-local) then publishes flag[g][slice][wave] (relaxed agent store);
//     consumer polls its 44 flags lane-parallel (relaxed agent loads), then
//     l1_inv + plain b128 A-ring. NO __syncthreads in the 256-step loop.
//   - 176 blocks; swizzle g=bx&7, s=bx>>3; HW_REG_XCC_ID check selects fast
//     (same-XCD group) or slow (release/acquire agent) per group.
//   - d_ws: [8] grid barrier, [16..191] xcc, [256..1279] wave flags.
//
// Evidence ledger:
//   - R12: VALU heaters on 80 idle CUs = exact null -> DVFS theory dead.
//   - R13: fast=TRUE; dependent-FMA chain added FULL nominal cost -> full
//     clock; ~20K cyc/step = serial per-wave stream S + small hop h; only
//     ~2.8K is issue. No slack at the poll: producers run AHEAD of consumers.
//   - R15: agent atomics bypass L1 AND L2 (coherence point = L3/MALL).
//   - R17: sc0-only loads NEVER observe remote same-XCD stores (so sc0 does
//     not actually bypass L1 for loads). Only working cross-block
//     observation paths: agent atomics (L3) or l1_inv+plain (L2).
//   - R18 probe: RT_agent ~570-900 cyc; flag hop NOT the missing ~13K.
//     x-prefetch-after-poll reorder ~ 0 gain (R18-minus-probe ~= baseline).
//   - R19: nt emb loads regressed (destroyed 22x L2 reuse). VGPR stayed 68
//     at default target: declared prefetch structures NEVER materialize;
//     effective A-lookahead ~2 slots => ~20 serial A-load exposures/step.
//   - R20: amdgpu_waves_per_eu(1,1) raises allocator acceptance (68->180)
//     and B-hoist killed h-loop LDS conflicts (5.755e7->1.015e7), but 264
//     loop-carried B VGPRs SPILLED to scratch: +2.9us/step. LDS conflicts
//     proven NOT dominant.
//   - R21: full A-prefetch (176 regs intra-loop) also spilled (VGPR capped
//     132): +3.3us/step. So R19/R20/R21 all VOID as tests of the
//     A-lookahead theory — structure exceeded allocator acceptance.
//   - R22 (this round): the clean one-variable test. R11 baseline source
//     BYTE-IDENTICAL (ring-8, emb prefetch before poll, B in LDS) plus ONLY
//     amdgpu_waves_per_eu(1,1). Declared need ~140 regs is INSIDE the
//     measured acceptance (132-180) => ring should materialize, no spill.
//     Decode: VGPR ~120-160 & dur ~1450-1700 => A-exposure was the stall
//     (go deeper next). VGPR ~140 & dur ~2080 => A-lookahead falsified on a
//     valid test -> next round replication-probes l1_inv (last unmeasured
//     primitive). VGPR >=180 or dur regress => allocator hurt; revert.
// ---------------------------------------------------------------------------

typedef unsigned short ushort_t;
typedef __bf16 bf16x8 __attribute__((ext_vector_type(8)));
typedef unsigned short ushort8 __attribute__((ext_vector_type(8)));
typedef float floatx4 __attribute__((ext_vector_type(4)));

#define NGRP   8
#define NSLC   22
#define NBLK   176
#define SB     840   // LDS row stride (bf16): 832 + 8 pad
#define HP     704
#define AH_ROW 1408  // hi[704] | lo[704]
#define PHASE  (256 * AH_ROW)
#define FLAGW(gg, ss, ww) (256 + (gg) * 128 + (ss) * 4 + (ww))

__device__ __forceinline__ float bf2f(ushort_t u) {
    unsigned v = ((unsigned)u) << 16; float f; __builtin_memcpy(&f, &v, 4); return f;
}
__device__ __forceinline__ ushort_t f2bf(float f) {
    unsigned u; __builtin_memcpy(&u, &f, 4);
    unsigned r = u + 0x7fff + ((u >> 16) & 1);
    return (ushort_t)(r >> 16);
}
__device__ __forceinline__ bf16x8 ld8(const ushort_t* p) {
    return __builtin_bit_cast(bf16x8, *(const ushort8*)p);
}
__device__ __forceinline__ bf16x8 cvt8(floatx4 a, floatx4 b) {
    ushort8 r = {f2bf(a.x), f2bf(a.y), f2bf(a.z), f2bf(a.w),
                 f2bf(b.x), f2bf(b.y), f2bf(b.z), f2bf(b.w)};
    return __builtin_bit_cast(bf16x8, r);
}
__device__ __forceinline__ void l1_inv() {
    asm volatile("buffer_inv sc0" ::: "memory");
}
__device__ __forceinline__ void wave_drain() {   // wave-local store drain
    asm volatile("s_waitcnt vmcnt(0)" ::: "memory");
}
__device__ __forceinline__ float fast_rcp(float x) {
    float r; asm("v_rcp_f32 %0, %1" : "=v"(r) : "v"(x)); return r;
}
__device__ __forceinline__ float fast_exp(float x) {
    float r; asm("v_exp_f32 %0, %1" : "=v"(r) : "v"(x * 1.44269504f)); return r;
}

__global__ void init_cnt(int* cnt) {
    for (int i = threadIdx.x; i < 1280; i += 1024) cnt[i] = 0;
}

__global__ __attribute__((amdgpu_waves_per_eu(1, 1)))
__launch_bounds__(256) void gru_main(
    const int* __restrict__ enc, const float* __restrict__ emb,
    const float* __restrict__ Wx, float* whf,
    const float* __restrict__ lab, const float* __restrict__ W1,
    const float* __restrict__ b1, const float* __restrict__ bias,
    float* __restrict__ out, int* cnt) {

    extern __shared__ ushort_t Bs[];   // [96][SB] bf16
    const int bx = blockIdx.x;
    const int g = bx & 7, s = bx >> 3;
    const int tid = threadIdx.x;
    const int wave = tid >> 6, lane = tid & 63;
    const int rt = wave >> 1, ct = wave & 1;
    const int q = lane >> 4, m = lane & 15;

    // ---- one-time staging: Bs[p][k] = bf16(W[k][col(p)]), p = gate*32+c ----
    for (int idx = tid; idx < 96 * 832; idx += 256) {
        int p = idx % 96, k = idx / 96;
        int c = s * 32 + (p & 31);
        ushort_t v = 0;
        if (c < 700) {
            int col = (p >> 5) * 700 + c;
            if (k < 100) v = f2bf(Wx[k * 2100 + col]);
            else if (k >= 128 && k < 828) v = f2bf(whf[(k - 128) * 2100 + col]);
        }
        Bs[p * SB + k] = v;
    }
    __syncthreads();   // all Wh reads of this block retired

    // ---- publish xcc id, then grid barrier (agent scope, one-time) ---------
    if (tid == 0) {
        int xcc;
        asm("s_getreg_b32 %0, hwreg(HW_REG_XCC_ID)" : "=s"(xcc));
        __hip_atomic_store(cnt + 16 + bx, xcc, __ATOMIC_RELAXED, __HIP_MEMORY_SCOPE_AGENT);
        __hip_atomic_fetch_add(cnt + 8, 1, __ATOMIC_ACQ_REL, __HIP_MEMORY_SCOPE_AGENT);
        while (__hip_atomic_load(cnt + 8, __ATOMIC_ACQUIRE, __HIP_MEMORY_SCOPE_AGENT) < NBLK)
            __builtin_amdgcn_s_sleep(1);
    }
    __syncthreads();

    // ---- fast iff all 22 peers share an XCD --------------------------------
    bool fast = true;
    {
        int myx = __hip_atomic_load(cnt + 16 + bx, __ATOMIC_RELAXED, __HIP_MEMORY_SCOPE_AGENT);
        for (int s2 = 0; s2 < NSLC; ++s2) {
            int px = __hip_atomic_load(cnt + 16 + g + 8 * s2, __ATOMIC_RELAXED, __HIP_MEMORY_SCOPE_AGENT);
            fast = fast && (px == myx);
        }
    }

    const int j = s * 32 + ct * 16 + m;
    float bzc = 0.f, brc = 0.f, b0h = 0.f, b1h = 0.f;
    if (j < 700) {
        bzc = bias[j] + bias[2100 + j];
        brc = bias[700 + j] + bias[2800 + j];
        b0h = bias[1400 + j];
        b1h = bias[3500 + j];
    }
    const int rowa = g * 32 + rt * 16 + m;

    ushort_t* Ah = (ushort_t*)whf;
    int* myflag = cnt + FLAGW(g, s, wave);
    // consumer wave rt needs flags (s2, rt*2+ct') for s2=0..21, ct'=0..1
    int* pollp = (lane < 44)
               ? (cnt + FLAGW(g, lane >> 1, rt * 2 + (lane & 1)))
               : (int*)nullptr;

    // ---- h0; publish hi/lo to phase 0 (per-wave) ---------------------------
    float hown[4];
#pragma unroll
    for (int i = 0; i < 4; i++) {
        int rowc = g * 32 + rt * 16 + q * 4 + i;
        float v = 0.f;
        if (j < 200) v = lab[rowc] * W1[j] + b1[j];
        hown[i] = v;
        ushort_t hi = f2bf(v);
        Ah[rowc * AH_ROW + j] = hi;
        Ah[rowc * AH_ROW + HP + j] = f2bf(v - bf2f(hi));
    }
    if (fast) {
        wave_drain();
        if (lane == 0)
            __hip_atomic_store(myflag, 1, __ATOMIC_RELAXED, __HIP_MEMORY_SCOPE_AGENT);
    } else {
        if (lane == 0)
            __hip_atomic_store(myflag, 1, __ATOMIC_RELEASE, __HIP_MEMORY_SCOPE_AGENT);
        else
            __threadfence();
    }

    const ushort_t* bsz = Bs + (ct * 16 + m) * SB;
    const ushort_t* bsr = Bs + (32 + ct * 16 + m) * SB;
    const ushort_t* bsh = Bs + (64 + ct * 16 + m) * SB;

    // ---- initial x prefetch for t=0 ----------------------------------------
    floatx4 pf[6]; floatx4 pft;
    {
        int tok = enc[rowa * 256 + 0];
        const float* ep = emb + tok * 100;
#pragma unroll
        for (int kt = 0; kt < 3; ++kt) {
            pf[kt * 2]     = *(const floatx4*)(ep + kt * 32 + q * 8);
            pf[kt * 2 + 1] = *(const floatx4*)(ep + kt * 32 + q * 8 + 4);
        }
        pft = *(const floatx4*)(ep + 96);
    }

    for (int t = 0; t < 256; ++t) {
        const ushort_t* Asrc = Ah + (t & 1) * PHASE;
        ushort_t* Adst = Ah + ((t + 1) & 1) * PHASE;
        floatx4 accz = {0,0,0,0}, accr = {0,0,0,0}, accrh = {0,0,0,0}, accxh = {0,0,0,0};

        // x-part from prefetched registers (off the critical chain)
#pragma unroll
        for (int kt = 0; kt < 3; ++kt) {
            bf16x8 a = cvt8(pf[kt * 2], pf[kt * 2 + 1]);
            int kb = kt * 32 + q * 8;
            accz  = __builtin_amdgcn_mfma_f32_16x16x32_bf16(a, ld8(bsz + kb), accz, 0, 0, 0);
            accr  = __builtin_amdgcn_mfma_f32_16x16x32_bf16(a, ld8(bsr + kb), accr, 0, 0, 0);
            accxh = __builtin_amdgcn_mfma_f32_16x16x32_bf16(a, ld8(bsh + kb), accxh, 0, 0, 0);
        }
        {
            ushort8 t8 = {0, 0, 0, 0, 0, 0, 0, 0};
            if (q == 0) {
                t8[0] = f2bf(pft.x); t8[1] = f2bf(pft.y);
                t8[2] = f2bf(pft.z); t8[3] = f2bf(pft.w);
            }
            bf16x8 a = __builtin_bit_cast(bf16x8, t8);
            int kb = 96 + q * 8;
            accz  = __builtin_amdgcn_mfma_f32_16x16x32_bf16(a, ld8(bsz + kb), accz, 0, 0, 0);
            accr  = __builtin_amdgcn_mfma_f32_16x16x32_bf16(a, ld8(bsr + kb), accr, 0, 0, 0);
            accxh = __builtin_amdgcn_mfma_f32_16x16x32_bf16(a, ld8(bsh + kb), accxh, 0, 0, 0);
        }
        // prefetch x for t+1 (in flight during the wait)
        {
            int tn = (t < 255) ? t + 1 : 255;
            int tok = enc[rowa * 256 + tn];
            const float* ep = emb + tok * 100;
#pragma unroll
            for (int kt = 0; kt < 3; ++kt) {
                pf[kt * 2]     = *(const floatx4*)(ep + kt * 32 + q * 8);
                pf[kt * 2 + 1] = *(const floatx4*)(ep + kt * 32 + q * 8 + 4);
            }
            pft = *(const floatx4*)(ep + 96);
        }

        // wait (per-wave, lane-parallel over the 44 relevant producer waves)
        if (lane < 44) {
            if (fast) {
                int spin = 0;
                while (__hip_atomic_load(pollp, __ATOMIC_RELAXED, __HIP_MEMORY_SCOPE_AGENT) < t + 1) {
                    if (++spin > 64) __builtin_amdgcn_s_sleep(1);
                }
            } else {
                while (__hip_atomic_load(pollp, __ATOMIC_ACQUIRE, __HIP_MEMORY_SCOPE_AGENT) < t + 1)
                    __builtin_amdgcn_s_sleep(1);
            }
        }
        if (fast) l1_inv();   // fresh L1 for this wave's h reads

        // h-part: 22 K-tiles; ring-buffer prefetch depth 8 of hi/lo A-frags
        const ushort_t* arow = Asrc + rowa * AH_ROW + q * 8;
        bf16x8 ra[8], rb[8];
#pragma unroll
        for (int p = 0; p < 8; ++p) {
            ra[p] = ld8(arow + p * 32);
            rb[p] = ld8(arow + HP + p * 32);
        }
#pragma unroll
        for (int kt = 0; kt < 22; ++kt) {
            bf16x8 ahi = ra[kt & 7];
            bf16x8 alo = rb[kt & 7];
            if (kt + 8 < 22) {
                ra[kt & 7] = ld8(arow + (kt + 8) * 32);
                rb[kt & 7] = ld8(arow + HP + (kt + 8) * 32);
            }
            int kb = 128 + kt * 32 + q * 8;
            bf16x8 bz8 = ld8(bsz + kb), br8 = ld8(bsr + kb), bh8 = ld8(bsh + kb);
            accz  = __builtin_amdgcn_mfma_f32_16x16x32_bf16(ahi, bz8, accz, 0, 0, 0);
            accr  = __builtin_amdgcn_mfma_f32_16x16x32_bf16(ahi, br8, accr, 0, 0, 0);
            accrh = __builtin_amdgcn_mfma_f32_16x16x32_bf16(ahi, bh8, accrh, 0, 0, 0);
            accz  = __builtin_amdgcn_mfma_f32_16x16x32_bf16(alo, bz8, accz, 0, 0, 0);
            accr  = __builtin_amdgcn_mfma_f32_16x16x32_bf16(alo, br8, accr, 0, 0, 0);
            accrh = __builtin_amdgcn_mfma_f32_16x16x32_bf16(alo, bh8, accrh, 0, 0, 0);
        }

        // epilogue: fast gates, update h, publish hi/lo
#pragma unroll
        for (int i = 0; i < 4; i++) {
            int rowc = g * 32 + rt * 16 + q * 4 + i;
            float z = fast_rcp(1.f + fast_exp(-(accz[i] + bzc)));
            float r = fast_rcp(1.f + fast_exp(-(accr[i] + brc)));
            float e2 = fast_exp(2.f * (accxh[i] + b0h + r * (accrh[i] + b1h)));
            float hh = 1.f - 2.f * fast_rcp(e2 + 1.f);
            float h = z * hown[i] + (1.f - z) * hh;
            if (j >= 700) h = 0.f;
            hown[i] = h;
            ushort_t hi = f2bf(h);
            Adst[rowc * AH_ROW + j] = hi;
            Adst[rowc * AH_ROW + HP + j] = f2bf(h - bf2f(hi));
        }

        // per-wave publish: drain own stores, then flag
        if (fast) {
            wave_drain();
            if (lane == 0)
                __hip_atomic_store(myflag, t + 2, __ATOMIC_RELAXED, __HIP_MEMORY_SCOPE_AGENT);
        } else {
            if (lane == 0)
                __hip_atomic_store(myflag, t + 2, __ATOMIC_RELEASE, __HIP_MEMORY_SCOPE_AGENT);
            else
                __threadfence();
        }
    }

    // ---- final output -------------------------------------------------------
#pragma unroll
    for (int i = 0; i < 4; i++) {
        int rowc = g * 32 + rt * 16 + q * 4 + i;
        if (j >= 200 && j < 700)
            out[rowc * 500 + (j - 200)] = hown[i];
    }
}

extern "C" void kernel_launch(void* const* d_in, const int* in_sizes, int n_in,
                              void* d_out, int out_size, void* d_ws, size_t ws_size,
                              hipStream_t stream) {
    (void)in_sizes; (void)n_in; (void)out_size; (void)ws_size;
    const int*   enc  = (const int*)d_in[0];
    const float* lab  = (const float*)d_in[1];
    const float* emb  = (const float*)d_in[2];
    const float* W1   = (const float*)d_in[3];
    const float* b1   = (const float*)d_in[4];
    const float* Wx   = (const float*)d_in[5];
    float*       Wh   = (float*)d_in[6];
    const float* bias = (const float*)d_in[7];

    int*   cnt = (int*)d_ws;               // 5.2 KB of scratch used
    float* out = (float*)d_out;

    init_cnt<<<1, 1024, 0, stream>>>(cnt);

    hipFuncSetAttribute((const void*)gru_main,
                        hipFuncAttributeMaxDynamicSharedMemorySize, 96 * SB * 2);
    gru_main<<<NBLK, 256, 96 * SB * 2, stream>>>(enc, emb, Wx, Wh, lab, W1, b1,
                                                 bias, out, cnt);
}

// Round 12
// 1930.109 us; speedup vs baseline: 1.5160x; 1.0055x over previous
//
#include <hip/hip_runtime.h>

// ---------------------------------------------------------------------------
// Encoder: x=emb[enc]; xp = x@Wx + b_in; reset-after GRU over T=256 steps;
// out = h_last[:, 200:700].  All float inputs fp32; output fp32.
//
// Persistent weight-stationary GRU, per-WAVE dataflow sync (R11 fabric):
//   - Consumer wave rt reads ONLY its own 16 rows, produced by same-rt waves
//     of the 22 producer blocks. Producer drains own stores (vmcnt(0) is
//     wave-local) then publishes flag[g][slice][wave] (relaxed agent store);
//     consumer polls its 44 flags lane-parallel (relaxed agent loads), then
//     plain b128 A-ring (L1 freshness via end-of-step l1_inv, R23).
//   - 176 blocks; swizzle g=bx&7, s=bx>>3; HW_REG_XCC_ID check selects fast
//     (same-XCD group) or slow (release/acquire agent) per group.
//   - d_ws: [8] grid barrier, [16..191] xcc, [256..1279] wave flags.
//
// Evidence ledger:
//   - R12: VALU heaters on 80 idle CUs = exact null -> DVFS theory dead.
//   - R13: fast=TRUE; dependent-FMA chain added FULL nominal cost -> full
//     clock; ~20K cyc/step = serial per-wave stream S + small hop h.
//   - R15: agent atomics bypass L1 AND L2 (coherence point = L3/MALL).
//   - R17: sc0-only flag pairs never observed; only working cross-block
//     observation: agent atomics (L3) or l1_inv+plain (L2).
//   - R18 probe: RT_agent ~570-900 cyc; flag hop NOT the missing ~13K.
//   - R19: nt emb loads regressed (22x L2 reuse destroyed). VGPR stayed 68
//     at default: prefetch structures never materialized (lookahead ~2).
//   - R20/R21: B-hoist (264 regs) and full-A (176 regs + ~100 live) both
//     crossed the 256 arch-VGPR ceiling -> scratch spill regressions. LDS
//     conflicts proven NOT dominant (R20: 5.755e7->1.015e7, no net gain).
//   - R22: R11 baseline + amdgpu_waves_per_eu(1,1) ONLY: VGPR 68->132,
//     ring-8 materialized, dur 2080->1940us (-7%). A-lookahead captured to
//     its register-feasible depth. Period 18.2K cyc/step, issue ~2.8K.
//   - R23 (this round): l1_inv is the LAST unmeasured per-step primitive
//     and currently sits at the worst point (right after flag detect, full
//     cost on the detect->A-load critical edge). Requirement is only that
//     inv executes between last A-read of step t and first A-read of t+1.
//     MOVE it to after the publish: overlaps store-drain shadow + next
//     x-part + poll. Flags are L1-bypassing agent atomics (unaffected);
//     pf/emb data lives in registers across the inv. One-time inv added
//     before the t-loop (step 0's A-reads must not hit stale staging-era
//     whf lines). Win-or-probe: dur -140..-240us => inv cost was real and
//     is now hidden; dur unchanged => inv tiny or non-overlappable (vmem
//     queue blocking) -> next round attacks flag contention / LDS pipe.
// ---------------------------------------------------------------------------

typedef unsigned short ushort_t;
typedef __bf16 bf16x8 __attribute__((ext_vector_type(8)));
typedef unsigned short ushort8 __attribute__((ext_vector_type(8)));
typedef float floatx4 __attribute__((ext_vector_type(4)));

#define NGRP   8
#define NSLC   22
#define NBLK   176
#define SB     840   // LDS row stride (bf16): 832 + 8 pad
#define HP     704
#define AH_ROW 1408  // hi[704] | lo[704]
#define PHASE  (256 * AH_ROW)
#define FLAGW(gg, ss, ww) (256 + (gg) * 128 + (ss) * 4 + (ww))

__device__ __forceinline__ float bf2f(ushort_t u) {
    unsigned v = ((unsigned)u) << 16; float f; __builtin_memcpy(&f, &v, 4); return f;
}
__device__ __forceinline__ ushort_t f2bf(float f) {
    unsigned u; __builtin_memcpy(&u, &f, 4);
    unsigned r = u + 0x7fff + ((u >> 16) & 1);
    return (ushort_t)(r >> 16);
}
__device__ __forceinline__ bf16x8 ld8(const ushort_t* p) {
    return __builtin_bit_cast(bf16x8, *(const ushort8*)p);
}
__device__ __forceinline__ bf16x8 cvt8(floatx4 a, floatx4 b) {
    ushort8 r = {f2bf(a.x), f2bf(a.y), f2bf(a.z), f2bf(a.w),
                 f2bf(b.x), f2bf(b.y), f2bf(b.z), f2bf(b.w)};
    return __builtin_bit_cast(bf16x8, r);
}
__device__ __forceinline__ void l1_inv() {
    asm volatile("buffer_inv sc0" ::: "memory");
}
__device__ __forceinline__ void wave_drain() {   // wave-local store drain
    asm volatile("s_waitcnt vmcnt(0)" ::: "memory");
}
__device__ __forceinline__ float fast_rcp(float x) {
    float r; asm("v_rcp_f32 %0, %1" : "=v"(r) : "v"(x)); return r;
}
__device__ __forceinline__ float fast_exp(float x) {
    float r; asm("v_exp_f32 %0, %1" : "=v"(r) : "v"(x * 1.44269504f)); return r;
}

__global__ void init_cnt(int* cnt) {
    for (int i = threadIdx.x; i < 1280; i += 1024) cnt[i] = 0;
}

__global__ __attribute__((amdgpu_waves_per_eu(1, 1)))
__launch_bounds__(256) void gru_main(
    const int* __restrict__ enc, const float* __restrict__ emb,
    const float* __restrict__ Wx, float* whf,
    const float* __restrict__ lab, const float* __restrict__ W1,
    const float* __restrict__ b1, const float* __restrict__ bias,
    float* __restrict__ out, int* cnt) {

    extern __shared__ ushort_t Bs[];   // [96][SB] bf16
    const int bx = blockIdx.x;
    const int g = bx & 7, s = bx >> 3;
    const int tid = threadIdx.x;
    const int wave = tid >> 6, lane = tid & 63;
    const int rt = wave >> 1, ct = wave & 1;
    const int q = lane >> 4, m = lane & 15;

    // ---- one-time staging: Bs[p][k] = bf16(W[k][col(p)]), p = gate*32+c ----
    for (int idx = tid; idx < 96 * 832; idx += 256) {
        int p = idx % 96, k = idx / 96;
        int c = s * 32 + (p & 31);
        ushort_t v = 0;
        if (c < 700) {
            int col = (p >> 5) * 700 + c;
            if (k < 100) v = f2bf(Wx[k * 2100 + col]);
            else if (k >= 128 && k < 828) v = f2bf(whf[(k - 128) * 2100 + col]);
        }
        Bs[p * SB + k] = v;
    }
    __syncthreads();   // all Wh reads of this block retired

    // ---- publish xcc id, then grid barrier (agent scope, one-time) ---------
    if (tid == 0) {
        int xcc;
        asm("s_getreg_b32 %0, hwreg(HW_REG_XCC_ID)" : "=s"(xcc));
        __hip_atomic_store(cnt + 16 + bx, xcc, __ATOMIC_RELAXED, __HIP_MEMORY_SCOPE_AGENT);
        __hip_atomic_fetch_add(cnt + 8, 1, __ATOMIC_ACQ_REL, __HIP_MEMORY_SCOPE_AGENT);
        while (__hip_atomic_load(cnt + 8, __ATOMIC_ACQUIRE, __HIP_MEMORY_SCOPE_AGENT) < NBLK)
            __builtin_amdgcn_s_sleep(1);
    }
    __syncthreads();

    // ---- fast iff all 22 peers share an XCD --------------------------------
    bool fast = true;
    {
        int myx = __hip_atomic_load(cnt + 16 + bx, __ATOMIC_RELAXED, __HIP_MEMORY_SCOPE_AGENT);
        for (int s2 = 0; s2 < NSLC; ++s2) {
            int px = __hip_atomic_load(cnt + 16 + g + 8 * s2, __ATOMIC_RELAXED, __HIP_MEMORY_SCOPE_AGENT);
            fast = fast && (px == myx);
        }
    }

    const int j = s * 32 + ct * 16 + m;
    float bzc = 0.f, brc = 0.f, b0h = 0.f, b1h = 0.f;
    if (j < 700) {
        bzc = bias[j] + bias[2100 + j];
        brc = bias[700 + j] + bias[2800 + j];
        b0h = bias[1400 + j];
        b1h = bias[3500 + j];
    }
    const int rowa = g * 32 + rt * 16 + m;

    ushort_t* Ah = (ushort_t*)whf;
    int* myflag = cnt + FLAGW(g, s, wave);
    // consumer wave rt needs flags (s2, rt*2+ct') for s2=0..21, ct'=0..1
    int* pollp = (lane < 44)
               ? (cnt + FLAGW(g, lane >> 1, rt * 2 + (lane & 1)))
               : (int*)nullptr;

    // ---- h0; publish hi/lo to phase 0 (per-wave) ---------------------------
    float hown[4];
#pragma unroll
    for (int i = 0; i < 4; i++) {
        int rowc = g * 32 + rt * 16 + q * 4 + i;
        float v = 0.f;
        if (j < 200) v = lab[rowc] * W1[j] + b1[j];
        hown[i] = v;
        ushort_t hi = f2bf(v);
        Ah[rowc * AH_ROW + j] = hi;
        Ah[rowc * AH_ROW + HP + j] = f2bf(v - bf2f(hi));
    }
    if (fast) {
        wave_drain();
        if (lane == 0)
            __hip_atomic_store(myflag, 1, __ATOMIC_RELAXED, __HIP_MEMORY_SCOPE_AGENT);
    } else {
        if (lane == 0)
            __hip_atomic_store(myflag, 1, __ATOMIC_RELEASE, __HIP_MEMORY_SCOPE_AGENT);
        else
            __threadfence();
    }

    const ushort_t* bsz = Bs + (ct * 16 + m) * SB;
    const ushort_t* bsr = Bs + (32 + ct * 16 + m) * SB;
    const ushort_t* bsh = Bs + (64 + ct * 16 + m) * SB;

    // ---- initial x prefetch for t=0 ----------------------------------------
    floatx4 pf[6]; floatx4 pft;
    {
        int tok = enc[rowa * 256 + 0];
        const float* ep = emb + tok * 100;
#pragma unroll
        for (int kt = 0; kt < 3; ++kt) {
            pf[kt * 2]     = *(const floatx4*)(ep + kt * 32 + q * 8);
            pf[kt * 2 + 1] = *(const floatx4*)(ep + kt * 32 + q * 8 + 4);
        }
        pft = *(const floatx4*)(ep + 96);
    }

    // ---- R23: one-time inv before the loop — step 0's A-reads must not hit
    // stale staging-era whf lines in L1 (per-step inv now at end of iter).
    if (fast) l1_inv();

    for (int t = 0; t < 256; ++t) {
        const ushort_t* Asrc = Ah + (t & 1) * PHASE;
        ushort_t* Adst = Ah + ((t + 1) & 1) * PHASE;
        floatx4 accz = {0,0,0,0}, accr = {0,0,0,0}, accrh = {0,0,0,0}, accxh = {0,0,0,0};

        // x-part from prefetched registers (off the critical chain)
#pragma unroll
        for (int kt = 0; kt < 3; ++kt) {
            bf16x8 a = cvt8(pf[kt * 2], pf[kt * 2 + 1]);
            int kb = kt * 32 + q * 8;
            accz  = __builtin_amdgcn_mfma_f32_16x16x32_bf16(a, ld8(bsz + kb), accz, 0, 0, 0);
            accr  = __builtin_amdgcn_mfma_f32_16x16x32_bf16(a, ld8(bsr + kb), accr, 0, 0, 0);
            accxh = __builtin_amdgcn_mfma_f32_16x16x32_bf16(a, ld8(bsh + kb), accxh, 0, 0, 0);
        }
        {
            ushort8 t8 = {0, 0, 0, 0, 0, 0, 0, 0};
            if (q == 0) {
                t8[0] = f2bf(pft.x); t8[1] = f2bf(pft.y);
                t8[2] = f2bf(pft.z); t8[3] = f2bf(pft.w);
            }
            bf16x8 a = __builtin_bit_cast(bf16x8, t8);
            int kb = 96 + q * 8;
            accz  = __builtin_amdgcn_mfma_f32_16x16x32_bf16(a, ld8(bsz + kb), accz, 0, 0, 0);
            accr  = __builtin_amdgcn_mfma_f32_16x16x32_bf16(a, ld8(bsr + kb), accr, 0, 0, 0);
            accxh = __builtin_amdgcn_mfma_f32_16x16x32_bf16(a, ld8(bsh + kb), accxh, 0, 0, 0);
        }
        // prefetch x for t+1 (in flight during the wait)
        {
            int tn = (t < 255) ? t + 1 : 255;
            int tok = enc[rowa * 256 + tn];
            const float* ep = emb + tok * 100;
#pragma unroll
            for (int kt = 0; kt < 3; ++kt) {
                pf[kt * 2]     = *(const floatx4*)(ep + kt * 32 + q * 8);
                pf[kt * 2 + 1] = *(const floatx4*)(ep + kt * 32 + q * 8 + 4);
            }
            pft = *(const floatx4*)(ep + 96);
        }

        // wait (per-wave, lane-parallel over the 44 relevant producer waves)
        if (lane < 44) {
            if (fast) {
                int spin = 0;
                while (__hip_atomic_load(pollp, __ATOMIC_RELAXED, __HIP_MEMORY_SCOPE_AGENT) < t + 1) {
                    if (++spin > 64) __builtin_amdgcn_s_sleep(1);
                }
            } else {
                while (__hip_atomic_load(pollp, __ATOMIC_ACQUIRE, __HIP_MEMORY_SCOPE_AGENT) < t + 1)
                    __builtin_amdgcn_s_sleep(1);
            }
        }
        // (R23: no inv here — L1 was invalidated at the end of the previous
        // iteration; nothing has touched A-addresses since.)

        // h-part: 22 K-tiles; ring-buffer prefetch depth 8 of hi/lo A-frags
        const ushort_t* arow = Asrc + rowa * AH_ROW + q * 8;
        bf16x8 ra[8], rb[8];
#pragma unroll
        for (int p = 0; p < 8; ++p) {
            ra[p] = ld8(arow + p * 32);
            rb[p] = ld8(arow + HP + p * 32);
        }
#pragma unroll
        for (int kt = 0; kt < 22; ++kt) {
            bf16x8 ahi = ra[kt & 7];
            bf16x8 alo = rb[kt & 7];
            if (kt + 8 < 22) {
                ra[kt & 7] = ld8(arow + (kt + 8) * 32);
                rb[kt & 7] = ld8(arow + HP + (kt + 8) * 32);
            }
            int kb = 128 + kt * 32 + q * 8;
            bf16x8 bz8 = ld8(bsz + kb), br8 = ld8(bsr + kb), bh8 = ld8(bsh + kb);
            accz  = __builtin_amdgcn_mfma_f32_16x16x32_bf16(ahi, bz8, accz, 0, 0, 0);
            accr  = __builtin_amdgcn_mfma_f32_16x16x32_bf16(ahi, br8, accr, 0, 0, 0);
            accrh = __builtin_amdgcn_mfma_f32_16x16x32_bf16(ahi, bh8, accrh, 0, 0, 0);
            accz  = __builtin_amdgcn_mfma_f32_16x16x32_bf16(alo, bz8, accz, 0, 0, 0);
            accr  = __builtin_amdgcn_mfma_f32_16x16x32_bf16(alo, br8, accr, 0, 0, 0);
            accrh = __builtin_amdgcn_mfma_f32_16x16x32_bf16(alo, bh8, accrh, 0, 0, 0);
        }

        // epilogue: fast gates, update h, publish hi/lo
#pragma unroll
        for (int i = 0; i < 4; i++) {
            int rowc = g * 32 + rt * 16 + q * 4 + i;
            float z = fast_rcp(1.f + fast_exp(-(accz[i] + bzc)));
            float r = fast_rcp(1.f + fast_exp(-(accr[i] + brc)));
            float e2 = fast_exp(2.f * (accxh[i] + b0h + r * (accrh[i] + b1h)));
            float hh = 1.f - 2.f * fast_rcp(e2 + 1.f);
            float h = z * hown[i] + (1.f - z) * hh;
            if (j >= 700) h = 0.f;
            hown[i] = h;
            ushort_t hi = f2bf(h);
            Adst[rowc * AH_ROW + j] = hi;
            Adst[rowc * AH_ROW + HP + j] = f2bf(h - bf2f(hi));
        }

        // per-wave publish: drain own stores, then flag
        if (fast) {
            wave_drain();
            if (lane == 0)
                __hip_atomic_store(myflag, t + 2, __ATOMIC_RELAXED, __HIP_MEMORY_SCOPE_AGENT);
        } else {
            if (lane == 0)
                __hip_atomic_store(myflag, t + 2, __ATOMIC_RELEASE, __HIP_MEMORY_SCOPE_AGENT);
            else
                __threadfence();
        }

        // ---- R23: end-of-step inv — L1 freshness for NEXT step's A-reads.
        // Overlaps the publish/poll phase instead of the detect->A edge.
        if (fast) l1_inv();
    }

    // ---- final output -------------------------------------------------------
#pragma unroll
    for (int i = 0; i < 4; i++) {
        int rowc = g * 32 + rt * 16 + q * 4 + i;
        if (j >= 200 && j < 700)
            out[rowc * 500 + (j - 200)] = hown[i];
    }
}

extern "C" void kernel_launch(void* const* d_in, const int* in_sizes, int n_in,
                              void* d_out, int out_size, void* d_ws, size_t ws_size,
                              hipStream_t stream) {
    (void)in_sizes; (void)n_in; (void)out_size; (void)ws_size;
    const int*   enc  = (const int*)d_in[0];
    const float* lab  = (const float*)d_in[1];
    const float* emb  = (const float*)d_in[2];
    const float* W1   = (const float*)d_in[3];
    const float* b1   = (const float*)d_in[4];
    const float* Wx   = (const float*)d_in[5];
    float*       Wh   = (float*)d_in[6];
    const float* bias = (const float*)d_in[7];

    int*   cnt = (int*)d_ws;               // 5.2 KB of scratch used
    float* out = (float*)d_out;

    init_cnt<<<1, 1024, 0, stream>>>(cnt);

    hipFuncSetAttribute((const void*)gru_main,
                        hipFuncAttributeMaxDynamicSharedMemorySize, 96 * SB * 2);
    gru_main<<<NBLK, 256, 96 * SB * 2, stream>>>(enc, emb, Wx, Wh, lab, W1, b1,
                                                 bias, out, cnt);
}